// Round 5
// baseline (17220.531 us; speedup 1.0000x reference)
//
#include <hip/hip_runtime.h>
#include <hip/hip_bf16.h>

#define N        2048
#define T_STEPS  8192
#define DIN      64
#define KW       128     // workgroups, 1 per CU
#define ROWS     16      // N / KW rows per WG
#define NTHR     256
#define SCOPE_AG __HIP_MEMORY_SCOPE_AGENT

typedef unsigned long long u64;
typedef unsigned int v4u __attribute__((ext_vector_type(4)));

// ---------------------------------------------------------------------------
// Exchange protocol: ex[t&1][k] (k in [0,2048)) holds s_t[k] as
// (fp32_bits<<32)|t — value and tag in one naturally-atomic 8-B atom.
// Producers: one relaxed agent-scope 64-bit store per element (no fence).
// Consumers: poll PAIRS of atoms with 16-B sc1 loads (L2-bypass, same flag
// the compiler emits for agent-scope atomics); each 8-B half self-validates
// via its tag, so any 16-B tearing is harmless. Depth-2 flow control: a slot
// can only advance to tag t+2 after ALL WGs consumed tag t (race-free).
// ---------------------------------------------------------------------------

__global__ void init_kernel(u64* ex0) {
    int i = threadIdx.x + blockIdx.x * blockDim.x;
    if (i < N) ex0[i] = 0ull;   // s_0 = 0.0f tagged 0; ex[1] keeps poison
                                // tags (0xAAAAAAAA matches no t in [0,8192]).
}

extern "C" __global__ void __launch_bounds__(NTHR, 1)
reservoir_scan(const float* __restrict__ W,
               const float* __restrict__ W_in,
               const float* __restrict__ u,
               const float* __restrict__ noise,
               u64* __restrict__ ex,                 // [2][N] value+tag atoms
               __hip_bfloat16* __restrict__ states)  // [T][N]
{
    __shared__ float s_s[2][N];  // double-buffered broadcast state (16 KiB)
    __shared__ int   s_timeout;

    const int tid = threadIdx.x;
    const int wg  = blockIdx.x;
    const int wv  = tid >> 6;        // wave 0..3
    const int ln  = tid & 63;        // lane 0..63
    const int r0  = wg * ROWS;       // first global row of this WG
    const int rb  = wv * 4;          // first local row of this wave

    // --- W slice into registers: wr[r][j] = W[r0+rb+r][4*(ln+64j) .. +3] ---
    float4 wr[4][8];
    const float4* W4 = (const float4*)W;
    #pragma unroll
    for (int r = 0; r < 4; ++r)
        #pragma unroll
        for (int j = 0; j < 8; ++j)
            wr[r][j] = W4[(size_t)(r0 + rb + r) * (N / 4) + ln + 64 * j];

    // --- W_in columns: lane ln holds W_in[row][ln] (DIN == 64) ---
    float wi0 = W_in[(size_t)(r0 + rb + 0) * DIN + ln];
    float wi1 = W_in[(size_t)(r0 + rb + 1) * DIN + ln];
    float wi2 = W_in[(size_t)(r0 + rb + 2) * DIN + ln];
    float wi3 = W_in[(size_t)(r0 + rb + 3) * DIN + ln];
    if (tid == 0) s_timeout = 0;
    __syncthreads();

    // this thread's 4 atom-pairs: p_i = wv*256 + 64i + ln  (covers all 1024)
    const int p0 = wv * 256 + ln;
    bool use_b128 = true;

    for (int t = 0; t < T_STEPS; ++t) {
        const int buf = t & 1;
        // pin W in VGPRs every iteration (scalar-component form — float4
        // "+v" ties are rejected by LLVM). Spilling would cost 128 scratch
        // reloads per step, so the allocator keeps the slice resident.
        #pragma unroll
        for (int r = 0; r < 4; ++r)
            #pragma unroll
            for (int j = 0; j < 8; ++j)
                asm volatile("" : "+v"(wr[r][j].x), "+v"(wr[r][j].y),
                                  "+v"(wr[r][j].z), "+v"(wr[r][j].w));

        // independent loads issued early — overlap with the spin-gather
        float ul = u[t * DIN + ln];
        float nz = 0.0f;
        if (ln < 4) nz = noise[(size_t)t * N + r0 + rb + ln];

        u64* exb = ex + (size_t)buf * N;
        bool got = false;

        if (use_b128) {
            const u64* a0 = exb + 2 * (p0);
            const u64* a1 = exb + 2 * (p0 + 64);
            const u64* a2 = exb + 2 * (p0 + 128);
            const u64* a3 = exb + 2 * (p0 + 192);
            v4u q0, q1, q2, q3;
            int g = 0;
            for (;;) {
                asm volatile("global_load_dwordx4 %0, %1, off sc1" : "=v"(q0) : "v"(a0));
                asm volatile("global_load_dwordx4 %0, %1, off sc1" : "=v"(q1) : "v"(a1));
                asm volatile("global_load_dwordx4 %0, %1, off sc1" : "=v"(q2) : "v"(a2));
                asm volatile("global_load_dwordx4 %0, %1, off sc1" : "=v"(q3) : "v"(a3));
                asm volatile("s_waitcnt vmcnt(0)" ::: "memory");
                int ok = (q0.x == (unsigned)t) + (q0.z == (unsigned)t)
                       + (q1.x == (unsigned)t) + (q1.z == (unsigned)t)
                       + (q2.x == (unsigned)t) + (q2.z == (unsigned)t)
                       + (q3.x == (unsigned)t) + (q3.z == (unsigned)t);
                if (__all(ok == 8)) { got = true; break; }
                if (++g > 2048) { use_b128 = false; break; }  // sc1 hedge
            }
            if (got) {
                *(float2*)&s_s[buf][2 * (p0      )] = make_float2(__uint_as_float(q0.y), __uint_as_float(q0.w));
                *(float2*)&s_s[buf][2 * (p0 +  64)] = make_float2(__uint_as_float(q1.y), __uint_as_float(q1.w));
                *(float2*)&s_s[buf][2 * (p0 + 128)] = make_float2(__uint_as_float(q2.y), __uint_as_float(q2.w));
                *(float2*)&s_s[buf][2 * (p0 + 192)] = make_float2(__uint_as_float(q3.y), __uint_as_float(q3.w));
            }
        }
        if (!got) {
            // proven per-atom path (also the permanent fallback if sc1 ever
            // fails to provide cross-XCD freshness)
            unsigned pend = 0xFFu;
            int guard = 0;
            while (pend) {
                #pragma unroll
                for (int h = 0; h < 8; ++h) {
                    if (pend & (1u << h)) {
                        int atom = 2 * (p0 + 64 * (h >> 1)) + (h & 1);
                        u64 v = __hip_atomic_load(&exb[atom], __ATOMIC_RELAXED, SCOPE_AG);
                        if ((unsigned)v == (unsigned)t) {
                            s_s[buf][atom] = __uint_as_float((unsigned)(v >> 32));
                            pend &= ~(1u << h);
                        }
                    }
                }
                if (++guard > (1 << 17)) { s_timeout = 1; break; }
            }
        }

        __syncthreads();          // single barrier per step (s_s is dbuf'd)
        if (s_timeout) return;    // uniform abort instead of an eternal hang

        // --- matvec: wave wv -> rows rb..rb+3; lane covers cols {4(ln+64j)} ---
        const float4* s4 = (const float4*)&s_s[buf][0];
        float a0 = wi0 * ul;      // input drive folded into the same reduction
        float a1 = wi1 * ul;
        float a2 = wi2 * ul;
        float a3 = wi3 * ul;
        #pragma unroll
        for (int j = 0; j < 8; ++j) {
            float4 sv = s4[ln + 64 * j];
            a0 += wr[0][j].x * sv.x + wr[0][j].y * sv.y + wr[0][j].z * sv.z + wr[0][j].w * sv.w;
            a1 += wr[1][j].x * sv.x + wr[1][j].y * sv.y + wr[1][j].z * sv.z + wr[1][j].w * sv.w;
            a2 += wr[2][j].x * sv.x + wr[2][j].y * sv.y + wr[2][j].z * sv.z + wr[2][j].w * sv.w;
            a3 += wr[3][j].x * sv.x + wr[3][j].y * sv.y + wr[3][j].z * sv.z + wr[3][j].w * sv.w;
        }
        #pragma unroll
        for (int off = 1; off < 64; off <<= 1) {
            a0 += __shfl_xor(a0, off, 64);
            a1 += __shfl_xor(a1, off, 64);
            a2 += __shfl_xor(a2, off, 64);
            a3 += __shfl_xor(a3, off, 64);
        }

        if (ln < 4) {
            const int gr = r0 + rb + ln;
            float acc = (ln == 0) ? a0 : (ln == 1) ? a1 : (ln == 2) ? a2 : a3;
            float pre = acc + 0.01f * nz;
            // fast tanh: sign * (1 - 2/(exp2(2*log2e*|x|)+1))
            float ax = __builtin_fabsf(pre);
            float e  = __builtin_amdgcn_exp2f(ax * 2.8853900817779268f);
            float th = 1.0f - 2.0f * __builtin_amdgcn_rcpf(e + 1.0f);
            th = __builtin_copysignf(th, pre);
            float snew = 0.7f * s_s[buf][gr] + 0.3f * th;
            u64 pk = ((u64)__float_as_uint(snew) << 32) | (unsigned)(t + 1);
            __hip_atomic_store(&ex[(size_t)(buf ^ 1) * N + gr], pk,
                               __ATOMIC_RELAXED, SCOPE_AG);
            states[(size_t)t * N + gr] = __float2bfloat16(snew);
        }
        // no trailing barrier: a wave reaching step t+2 (overwriting
        // s_s[buf]) requires all 4 waves to have stored step t+1, which
        // implies their reads of s_s[buf] completed.
    }
}

// ---------------------------------------------------------------------------
// readout: out[t][d] = states[t] . w_out[d] + b_out[d].
// ---------------------------------------------------------------------------
__global__ void __launch_bounds__(256)
out_gemm(const __hip_bfloat16* __restrict__ states,
         const float* __restrict__ w_out,
         const float* __restrict__ b_out,
         float* __restrict__ out)
{
    __shared__ float s_lds[4][N];   // 32 KiB
    const int tid = threadIdx.x;
    const int wv  = tid >> 6, ln = tid & 63;
    const int t0  = blockIdx.x * 4;

    for (int idx = tid; idx < 4 * N; idx += 256) {
        int tt = idx >> 11, kk = idx & (N - 1);
        s_lds[tt][kk] = __bfloat162float(states[(size_t)(t0 + tt) * N + kk]);
    }
    __syncthreads();

    const int t = t0 + wv;
    const float4* s4 = (const float4*)&s_lds[wv][0];
    for (int d = 0; d < 64; ++d) {
        const float4* w4 = (const float4*)(w_out + (size_t)d * N);
        float a = 0.0f;
        #pragma unroll
        for (int j = 0; j < 8; ++j) {
            const int ci = ln + 64 * j;
            float4 wv4 = w4[ci];
            float4 sv  = s4[ci];
            a += wv4.x * sv.x + wv4.y * sv.y + wv4.z * sv.z + wv4.w * sv.w;
        }
        #pragma unroll
        for (int off = 1; off < 64; off <<= 1) a += __shfl_xor(a, off, 64);
        if (ln == 0) out[t * 64 + d] = a + b_out[d];
    }
}

// ---------------------------------------------------------------------------
extern "C" void kernel_launch(void* const* d_in, const int* in_sizes, int n_in,
                              void* d_out, int out_size, void* d_ws, size_t ws_size,
                              hipStream_t stream)
{
    const float* u     = (const float*)d_in[0];   // (T, DIN)
    const float* noise = (const float*)d_in[1];   // (T, N)
    const float* W_in  = (const float*)d_in[2];   // (N, DIN)
    const float* W     = (const float*)d_in[3];   // (N, N)
    const float* w_out = (const float*)d_in[4];   // (64, N)
    const float* b_out = (const float*)d_in[5];   // (64,)
    float* out = (float*)d_out;

    // workspace: [0, 32K): ex[2][N] u64 | [64K, 64K+32M): states bf16
    u64* ex                = (u64*)d_ws;
    __hip_bfloat16* states = (__hip_bfloat16*)((char*)d_ws + 65536);

    hipLaunchKernelGGL(init_kernel, dim3((N + 255) / 256), dim3(256), 0, stream,
                       ex);

    void* args[] = { (void*)&W, (void*)&W_in, (void*)&u, (void*)&noise,
                     (void*)&ex, (void*)&states };
    hipLaunchCooperativeKernel((const void*)reservoir_scan,
                               dim3(KW), dim3(NTHR), args, 0, stream);

    hipLaunchKernelGGL(out_gemm, dim3(T_STEPS / 4), dim3(256), 0, stream,
                       states, w_out, b_out, out);
}

// Round 6
// 12235.211 us; speedup vs baseline: 1.4075x; 1.4075x over previous
//
#include <hip/hip_runtime.h>
#include <hip/hip_bf16.h>

#define N        2048
#define T_STEPS  8192
#define DIN      64
#define KW       128     // workgroups, 1 per CU
#define ROWS     16      // N / KW rows per WG
#define NTHR     256
#define CAP      320     // padded nonzeros per row (mean 205, sigma 13.6)
#define NNZL     20      // CAP / 16 nonzeros per lane (16-lane row groups)
#define SCOPE_AG __HIP_MEMORY_SCOPE_AGENT

typedef unsigned long long u64;
typedef unsigned int v4u __attribute__((ext_vector_type(4)));

// ---------------------------------------------------------------------------
// Exchange protocol: ex[t&1][k] holds s_t[k] as (fp32_bits<<32)|t — value and
// tag in one naturally-atomic 8-B atom. Producers: one relaxed agent-scope
// 64-bit store. Consumers: 16-B sc1 polls (each 8-B half self-validates via
// its tag; tearing harmless). Depth-2 flow control: a slot can only advance
// to tag t+2 after ALL WGs consumed tag t (race-free).
// ---------------------------------------------------------------------------

__global__ void init_kernel(u64* ex0) {
    int i = threadIdx.x + blockIdx.x * blockDim.x;
    if (i < N) ex0[i] = 0ull;   // s_0 = 0.0f tagged 0; ex[1] keeps poison
                                // tags (0xAAAAAAAA matches no t in [0,8192]).
}

extern "C" __global__ void __launch_bounds__(NTHR, 1)
reservoir_scan(const float* __restrict__ W,
               const float* __restrict__ W_in,
               const float* __restrict__ u,
               const float* __restrict__ noise,
               u64* __restrict__ ex,                 // [2][N] value+tag atoms
               __hip_bfloat16* __restrict__ states)  // [T][N]
{
    __shared__ u64   Wp[ROWS][CAP];   // 40 KB — sparse staging (init only)
    __shared__ float s_s[2][N];       // 16 KB — double-buffered state
    __shared__ int   s_timeout;

    const int tid = threadIdx.x;
    const int wg  = blockIdx.x;
    const int wv  = tid >> 6;        // wave 0..3
    const int ln  = tid & 63;        // lane 0..63
    const int r0  = wg * ROWS;       // first global row of this WG
    const int l   = ln & 15;         // lane-in-group
    const int g   = ln >> 4;         // row group 0..3
    const int lr  = wv * 4 + g;      // local row this group owns
    const int grow = r0 + lr;        // its global row

    // --- one-time sparse extraction: ballot-compact this wave's 4 rows ---
    for (int r = 0; r < 4; ++r) {
        const int xlr = wv * 4 + r;
        const size_t rowoff = (size_t)(r0 + xlr) * N;
        int base = 0;
        for (int ch = 0; ch < 32; ++ch) {
            int col = ch * 64 + ln;
            float w = W[rowoff + col];
            u64 m = __ballot(w != 0.0f);
            if (w != 0.0f) {
                int pos = base + (int)__popcll(m & ((1ull << ln) - 1ull));
                if (pos < CAP)
                    Wp[xlr][pos] = ((u64)__float_as_uint(w) << 32) | (unsigned)col;
            }
            base += (int)__popcll(m);
        }
        for (int p = base + ln; p < CAP; p += 64)
            Wp[xlr][p] = 0ull;        // val=0, col=0 — contributes nothing
    }
    if (tid == 0) s_timeout = 0;
    __syncthreads();

    // --- sparse slice to registers: lane (g,l) takes row lr's slots l+16i ---
    u64 wreg[NNZL];
    #pragma unroll
    for (int i = 0; i < NNZL; ++i)
        wreg[i] = Wp[lr][l + 16 * i];

    // --- input-drive weights: win[j] = W_in[grow][l + 16j] ---
    float win[4];
    #pragma unroll
    for (int j = 0; j < 4; ++j)
        win[j] = W_in[(size_t)grow * DIN + l + 16 * j];
    __syncthreads();   // Wp dead from here

    // this thread's 4 atom-pairs for polling: p_i = wv*256 + 64i + ln
    const int p0 = wv * 256 + ln;
    bool use_b128 = true;

    for (int t = 0; t < T_STEPS; ++t) {
        const int buf = t & 1;

        // independent loads issued early — overlap with the spin-gather
        float ul = u[t * DIN + ln];
        float nz = 0.0f;
        if (l == 0) nz = noise[(size_t)t * N + grow];

        u64* exb = ex + (size_t)buf * N;
        bool got = false;

        if (use_b128) {
            const u64* a0 = exb + 2 * (p0);
            const u64* a1 = exb + 2 * (p0 + 64);
            const u64* a2 = exb + 2 * (p0 + 128);
            const u64* a3 = exb + 2 * (p0 + 192);
            v4u q0, q1, q2, q3;
            int gd = 0;
            for (;;) {
                asm volatile("global_load_dwordx4 %0, %1, off sc1" : "=v"(q0) : "v"(a0));
                asm volatile("global_load_dwordx4 %0, %1, off sc1" : "=v"(q1) : "v"(a1));
                asm volatile("global_load_dwordx4 %0, %1, off sc1" : "=v"(q2) : "v"(a2));
                asm volatile("global_load_dwordx4 %0, %1, off sc1" : "=v"(q3) : "v"(a3));
                asm volatile("s_waitcnt vmcnt(0)" ::: "memory");
                int ok = (q0.x == (unsigned)t) + (q0.z == (unsigned)t)
                       + (q1.x == (unsigned)t) + (q1.z == (unsigned)t)
                       + (q2.x == (unsigned)t) + (q2.z == (unsigned)t)
                       + (q3.x == (unsigned)t) + (q3.z == (unsigned)t);
                if (__all(ok == 8)) { got = true; break; }
                if (++gd > 2048) { use_b128 = false; break; }  // sc1 hedge
            }
            if (got) {
                *(float2*)&s_s[buf][2 * (p0      )] = make_float2(__uint_as_float(q0.y), __uint_as_float(q0.w));
                *(float2*)&s_s[buf][2 * (p0 +  64)] = make_float2(__uint_as_float(q1.y), __uint_as_float(q1.w));
                *(float2*)&s_s[buf][2 * (p0 + 128)] = make_float2(__uint_as_float(q2.y), __uint_as_float(q2.w));
                *(float2*)&s_s[buf][2 * (p0 + 192)] = make_float2(__uint_as_float(q3.y), __uint_as_float(q3.w));
            }
        }
        if (!got) {
            // proven per-atom fallback (also permanent if sc1 ever misbehaves)
            unsigned pend = 0xFFu;
            int guard = 0;
            while (pend) {
                #pragma unroll
                for (int h = 0; h < 8; ++h) {
                    if (pend & (1u << h)) {
                        int atom = 2 * (p0 + 64 * (h >> 1)) + (h & 1);
                        u64 v = __hip_atomic_load(&exb[atom], __ATOMIC_RELAXED, SCOPE_AG);
                        if ((unsigned)v == (unsigned)t) {
                            s_s[buf][atom] = __uint_as_float((unsigned)(v >> 32));
                            pend &= ~(1u << h);
                        }
                    }
                }
                if (++guard > (1 << 17)) { s_timeout = 1; break; }
            }
        }

        __syncthreads();          // single barrier per step (s_s is dbuf'd)
        if (s_timeout) return;    // uniform abort instead of an eternal hang

        // --- sparse matvec: 20 LDS gathers + 20 FMAs per lane ---
        float acc = 0.0f;
        #pragma unroll
        for (int i = 0; i < NNZL; ++i) {
            unsigned col = (unsigned)wreg[i];
            float    w   = __uint_as_float((unsigned)(wreg[i] >> 32));
            acc += w * s_s[buf][col];
        }
        // input drive: Sum_j W_in[grow][l+16j] * u[t][l+16j] via shuffles
        #pragma unroll
        for (int j = 0; j < 4; ++j)
            acc += win[j] * __shfl(ul, l + 16 * j, 64);
        // reduce within the 16-lane group (all 4 rows of the wave at once)
        #pragma unroll
        for (int off = 1; off < 16; off <<= 1)
            acc += __shfl_xor(acc, off, 64);

        if (l == 0) {
            float pre = acc + 0.01f * nz;
            // fast tanh: sign * (1 - 2/(exp2(2*log2e*|x|)+1))
            float ax = __builtin_fabsf(pre);
            float e  = __builtin_amdgcn_exp2f(ax * 2.8853900817779268f);
            float th = 1.0f - 2.0f * __builtin_amdgcn_rcpf(e + 1.0f);
            th = __builtin_copysignf(th, pre);
            float snew = 0.7f * s_s[buf][grow] + 0.3f * th;
            u64 pk = ((u64)__float_as_uint(snew) << 32) | (unsigned)(t + 1);
            __hip_atomic_store(&ex[(size_t)(buf ^ 1) * N + grow], pk,
                               __ATOMIC_RELAXED, SCOPE_AG);
            states[(size_t)t * N + grow] = __float2bfloat16(snew);
        }
        // no trailing barrier: overwriting s_s[buf] at step t+2 requires all
        // WGs' t+1 tags, which data-depend on their reads of s_s[buf].
    }
}

// ---------------------------------------------------------------------------
// readout: out[t][d] = states[t] . w_out[d] + b_out[d].
// ---------------------------------------------------------------------------
__global__ void __launch_bounds__(256)
out_gemm(const __hip_bfloat16* __restrict__ states,
         const float* __restrict__ w_out,
         const float* __restrict__ b_out,
         float* __restrict__ out)
{
    __shared__ float s_lds[4][N];   // 32 KiB
    const int tid = threadIdx.x;
    const int wv  = tid >> 6, ln = tid & 63;
    const int t0  = blockIdx.x * 4;

    for (int idx = tid; idx < 4 * N; idx += 256) {
        int tt = idx >> 11, kk = idx & (N - 1);
        s_lds[tt][kk] = __bfloat162float(states[(size_t)(t0 + tt) * N + kk]);
    }
    __syncthreads();

    const int t = t0 + wv;
    const float4* s4 = (const float4*)&s_lds[wv][0];
    for (int d = 0; d < 64; ++d) {
        const float4* w4 = (const float4*)(w_out + (size_t)d * N);
        float a = 0.0f;
        #pragma unroll
        for (int j = 0; j < 8; ++j) {
            const int ci = ln + 64 * j;
            float4 wv4 = w4[ci];
            float4 sv  = s4[ci];
            a += wv4.x * sv.x + wv4.y * sv.y + wv4.z * sv.z + wv4.w * sv.w;
        }
        #pragma unroll
        for (int off = 1; off < 64; off <<= 1) a += __shfl_xor(a, off, 64);
        if (ln == 0) out[t * 64 + d] = a + b_out[d];
    }
}

// ---------------------------------------------------------------------------
extern "C" void kernel_launch(void* const* d_in, const int* in_sizes, int n_in,
                              void* d_out, int out_size, void* d_ws, size_t ws_size,
                              hipStream_t stream)
{
    const float* u     = (const float*)d_in[0];   // (T, DIN)
    const float* noise = (const float*)d_in[1];   // (T, N)
    const float* W_in  = (const float*)d_in[2];   // (N, DIN)
    const float* W     = (const float*)d_in[3];   // (N, N)
    const float* w_out = (const float*)d_in[4];   // (64, N)
    const float* b_out = (const float*)d_in[5];   // (64,)
    float* out = (float*)d_out;

    // workspace: [0, 32K): ex[2][N] u64 | [64K, 64K+32M): states bf16
    u64* ex                = (u64*)d_ws;
    __hip_bfloat16* states = (__hip_bfloat16*)((char*)d_ws + 65536);

    hipLaunchKernelGGL(init_kernel, dim3((N + 255) / 256), dim3(256), 0, stream,
                       ex);

    void* args[] = { (void*)&W, (void*)&W_in, (void*)&u, (void*)&noise,
                     (void*)&ex, (void*)&states };
    hipLaunchCooperativeKernel((const void*)reservoir_scan,
                               dim3(KW), dim3(NTHR), args, 0, stream);

    hipLaunchKernelGGL(out_gemm, dim3(T_STEPS / 4), dim3(256), 0, stream,
                       states, w_out, b_out, out);
}